// Round 5
// baseline (228.704 us; speedup 1.0000x reference)
//
#include <hip/hip_runtime.h>
#include <hip/hip_bf16.h>
#include <hip/hip_fp8.h>

// Problem constants (fixed by the reference setup)
#define NN 50000     // nodes
#define NE 800000    // edges
#define FD 128       // feature dim (D_FEAT == DIM_H)
#define NG 512       // graphs
#define NC 10        // classes
#define NL 3         // layers
#define CAP 64       // bucket capacity (deg ~ Poisson(16); max over 50K ~ 33)
#define GEMM_B 782   // ceil(3125/4): 4 waves/block, 16 rows/wave
#define CVT_B 128    // (2*FD*FD)/256 weight-convert blocks (layers 1,2 only)
#define COMP_B 910   // GEMM_B + CVT_B
#define CHUNKS 782   // ceil(NE/1024): 1024 edges per scan chunk
#define NXCD 8
#define NODES_PER_XCD 6250   // NN/8
#define FRONT_B 8190 // 9*COMP_B; bid%9==0 -> gemm/cvt, else XCD-binned scatter
#define PATCH_B 12500 // NN*CAP/256

typedef unsigned short u16;
typedef unsigned char u8;
typedef unsigned int u32;
typedef short bf16x8 __attribute__((ext_vector_type(8)));
typedef float f32x4 __attribute__((ext_vector_type(4)));
typedef float f32x2 __attribute__((ext_vector_type(2)));

__device__ __forceinline__ float b2f(u16 v) {
    union { u32 u; float f; } c; c.u = ((u32)v) << 16; return c.f;
}
__device__ __forceinline__ u16 f2b(float f) {
    __hip_bfloat16 h = __float2bfloat16(f);   // RTNE
    return *(u16*)&h;
}
// OCP e4m3 (gfx950 HW cvt). B rows stored fp8 UNSCALED; the edge weight
// dinv[src] is PACKED (bf16) into the high 16 bits of each bucket entry by
// k_patch, so gathers pay ZERO extra loads for normalization.
__device__ __forceinline__ float p2f(u8 b) {
    __hip_fp8_e4m3 h; h.__x = b; return (float)h;
}
__device__ __forceinline__ u8 f2p(float f) {
    __hip_fp8_e4m3 h(f); return h.__x;
}

// HW packed fp8->f32 (2 lanes/instr). Word-select must be a template const
// (instruction immediate — R3 compile fail).
#if defined(__has_builtin)
#if __has_builtin(__builtin_amdgcn_cvt_pk_f32_fp8)
#define HAVE_PKCVT 1
#endif
#endif
template<bool HI>
__device__ __forceinline__ f32x2 pkcvt(u32 u) {
#ifdef HAVE_PKCVT
    return __builtin_amdgcn_cvt_pk_f32_fp8((int)u, HI);
#else
    f32x2 r;
    r[0] = p2f((u8)(HI ? (u >> 16) : u));
    r[1] = p2f((u8)(HI ? (u >> 24) : (u >> 8)));
    return r;
#endif
}

// ======== fused front-end: XCD-binned edge scatter + x@W0 GEMM + WT cvt ====
// R4 counters: WRITE 55MB for 9.6MB payload = ~16x line amplification — the
// random bkt scatter thrashes all 8 per-XCD L2s (12.8MB footprint each), so
// stores never merge. Fix: block bid handles only dst in octant bid&7 (the
// blockIdx%8 -> XCD round-robin heuristic); per-XCD bucket footprint drops to
// 1.6MB (L2-resident) so stores merge and write back dirty lines only.
// Each 1024-edge chunk is scanned by 8 blocks (one per XCD): +25.6MB
// coalesced dst fetch (~4us BW) buys ~-44MB scattered writes.
// Compute blocks ride 1-in-9 (period 9 rotates across XCDs — period 8 would
// pin all compute on XCD 0 and starve its scatter capacity).
__global__ __launch_bounds__(256) void k_front(const int* __restrict__ src,
                                               const int* __restrict__ dst,
                                               int* __restrict__ cnt,
                                               int* __restrict__ bkt,
                                               const float* __restrict__ W,
                                               u16* __restrict__ wt,
                                               const float* __restrict__ x,
                                               u8* __restrict__ Bout) {
    const int bid = blockIdx.x;
    if (bid % 9 == 0) {
        const int q = bid / 9;
        if (q < GEMM_B) {
            // ---- gemm0: x(fp32) @ W0 -> B0 (fp8, UNSCALED) ----
            // a_frag: A[m=lane&15][k=q*8+j]; b_frag: W[k][n=ct*16+m];
            // C/D: col=lane&15, row=q*4+reg   [verified m89/m91]
            const int wid = q * 4 + (threadIdx.x >> 6);
            if (wid >= 3125) return;
            const int row0 = wid * 16;
            const int lane = threadIdx.x & 63;
            const int m = lane & 15;
            const int qq = lane >> 4;
            f32x4 acc[8];
#pragma unroll
            for (int ct = 0; ct < 8; ++ct) acc[ct] = (f32x4){0.f, 0.f, 0.f, 0.f};
            const float* arow = x + (size_t)(row0 + m) * FD + qq * 8;
            const float* wbase = W + (size_t)qq * 8 * FD + m;
#pragma unroll
            for (int kb = 0; kb < 4; ++kb) {
                const float4 p0 = *(const float4*)(arow + kb * 32);
                const float4 p1 = *(const float4*)(arow + kb * 32 + 4);
                bf16x8 af;
                af[0] = (short)f2b(p0.x); af[1] = (short)f2b(p0.y);
                af[2] = (short)f2b(p0.z); af[3] = (short)f2b(p0.w);
                af[4] = (short)f2b(p1.x); af[5] = (short)f2b(p1.y);
                af[6] = (short)f2b(p1.z); af[7] = (short)f2b(p1.w);
#pragma unroll
                for (int ct = 0; ct < 8; ++ct) {
                    const float* wp = wbase + (size_t)kb * 32 * FD + ct * 16;
                    bf16x8 bf;
#pragma unroll
                    for (int j = 0; j < 8; ++j)
                        bf[j] = (short)f2b(wp[(size_t)j * FD]);
                    acc[ct] = __builtin_amdgcn_mfma_f32_16x16x32_bf16(af, bf,
                                                                      acc[ct], 0, 0, 0);
                }
            }
#pragma unroll
            for (int ct = 0; ct < 8; ++ct)
#pragma unroll
                for (int r = 0; r < 4; ++r)
                    Bout[(size_t)(row0 + qq * 4 + r) * FD + ct * 16 + m] =
                        f2p(acc[ct][r]);
        } else {
            // ---- WT convert, layers 1..2 only (layer 0 read raw above) ----
            const int c = (q - GEMM_B) * 256 + threadIdx.x + FD * FD;
            const int l = c >> 14, rr = c & 16383, k = rr >> 7, n = rr & 127;
            wt[(l << 14) + n * FD + k] = f2b(W[c]);
        }
        return;
    }
    // ---- XCD-binned scatter ----
    const int bin = bid & 7;          // presumed XCD id (round-robin)
    const int t = bid >> 3;           // prior blocks on this XCD
    // prior COMPUTE blocks on this XCD: bid' = 72u + 9*bin < bid
    const int m0 = 9 * bin;
    const int c9 = (bid > m0) ? ((bid - m0 - 1) / 72 + 1) : 0;
    const int chunk = t - c9;         // consecutive per-XCD scan index
    if (chunk >= CHUNKS) return;
    const int e0 = chunk * 1024 + (threadIdx.x << 2);
    if (e0 >= NE) return;             // NE%4==0 -> e0..e0+3 all in-bounds
    const int4 d4 = *(const int4*)(dst + e0);
    const int dd[4] = {d4.x, d4.y, d4.z, d4.w};
#pragma unroll
    for (int j = 0; j < 4; ++j) {
        const int d = dd[j];
        if ((u32)d / (u32)NODES_PER_XCD == (u32)bin) {
            const int s = src[e0 + j];             // predicated, 1/8 density
            const int slot = atomicAdd(&cnt[d], 1);
            if (slot < CAP) bkt[d * CAP + slot] = s;   // L2-local line now
        }
    }
}

// ======== bucket weight patch: entry := src | bf16(dinv[src]) << 16 ========
__global__ __launch_bounds__(256) void k_patch(const int* __restrict__ cnt,
                                               int* __restrict__ bkt) {
    const int i = blockIdx.x * 256 + threadIdx.x;   // NN*CAP exact
    const int d = i >> 6;
    const int s = i & 63;
    if (s < cnt[d]) {
        const int v = bkt[i];                       // raw src id (<50000, 16b)
        const u32 w = (u32)f2b(rsqrtf((float)(cnt[v] + 1)));
        bkt[i] = (int)(((u32)v & 0xFFFFu) | (w << 16));
    }
}

// ======== half-wave gather on UNSCALED fp8 rows (packed bucket CSR) ========
// h[n] = relu(di_n * (sum_in w_s*B[s] + di_n*B[n]) + bias); rows 128 B fp8.
// W8: 8 rows in flight (k_gg). k_gpool stays 4-wide: its 1024-thr blocks sit
// at the 2-blocks/CU VGPR cliff; 8-wide would halve gpool occupancy.
template<bool W8>
__device__ __forceinline__ float4 gather_node(const int rs, const int re,
                                              const int* __restrict__ bkt,
                                              const u8* __restrict__ B,
                                              const float di, const int n,
                                              const float4 bb, const int f) {
    const u32 us = *(const u32*)(B + (size_t)n * FD + f);   // self row (early)
    f32x2 aL0 = {0.f, 0.f}, aL1 = {0.f, 0.f}, aL2 = {0.f, 0.f}, aL3 = {0.f, 0.f};
    f32x2 aH0 = {0.f, 0.f}, aH1 = {0.f, 0.f}, aH2 = {0.f, 0.f}, aH3 = {0.f, 0.f};
    int e = rs;
    if (W8) {
        for (; e + 8 <= re; e += 8) {
            const int4 p0 = *(const int4*)(bkt + e);     // rs 16B-aligned
            const int4 p1 = *(const int4*)(bkt + e + 4);
            const u32 r0 = *(const u32*)(B + (size_t)(p0.x & 0xFFFF) * FD + f);
            const u32 r1 = *(const u32*)(B + (size_t)(p0.y & 0xFFFF) * FD + f);
            const u32 r2 = *(const u32*)(B + (size_t)(p0.z & 0xFFFF) * FD + f);
            const u32 r3 = *(const u32*)(B + (size_t)(p0.w & 0xFFFF) * FD + f);
            const u32 r4 = *(const u32*)(B + (size_t)(p1.x & 0xFFFF) * FD + f);
            const u32 r5 = *(const u32*)(B + (size_t)(p1.y & 0xFFFF) * FD + f);
            const u32 r6 = *(const u32*)(B + (size_t)(p1.z & 0xFFFF) * FD + f);
            const u32 r7 = *(const u32*)(B + (size_t)(p1.w & 0xFFFF) * FD + f);
            const float w0 = b2f((u16)((u32)p0.x >> 16));
            const float w1 = b2f((u16)((u32)p0.y >> 16));
            const float w2 = b2f((u16)((u32)p0.z >> 16));
            const float w3 = b2f((u16)((u32)p0.w >> 16));
            const float w4 = b2f((u16)((u32)p1.x >> 16));
            const float w5 = b2f((u16)((u32)p1.y >> 16));
            const float w6 = b2f((u16)((u32)p1.z >> 16));
            const float w7 = b2f((u16)((u32)p1.w >> 16));
            aL0 += pkcvt<false>(r0) * w0; aH0 += pkcvt<true>(r0) * w0;
            aL1 += pkcvt<false>(r1) * w1; aH1 += pkcvt<true>(r1) * w1;
            aL2 += pkcvt<false>(r2) * w2; aH2 += pkcvt<true>(r2) * w2;
            aL3 += pkcvt<false>(r3) * w3; aH3 += pkcvt<true>(r3) * w3;
            aL0 += pkcvt<false>(r4) * w4; aH0 += pkcvt<true>(r4) * w4;
            aL1 += pkcvt<false>(r5) * w5; aH1 += pkcvt<true>(r5) * w5;
            aL2 += pkcvt<false>(r6) * w6; aH2 += pkcvt<true>(r6) * w6;
            aL3 += pkcvt<false>(r7) * w7; aH3 += pkcvt<true>(r7) * w7;
        }
    }
    for (; e + 4 <= re; e += 4) {
        const int4 p0 = *(const int4*)(bkt + e);
        const u32 r0 = *(const u32*)(B + (size_t)(p0.x & 0xFFFF) * FD + f);
        const u32 r1 = *(const u32*)(B + (size_t)(p0.y & 0xFFFF) * FD + f);
        const u32 r2 = *(const u32*)(B + (size_t)(p0.z & 0xFFFF) * FD + f);
        const u32 r3 = *(const u32*)(B + (size_t)(p0.w & 0xFFFF) * FD + f);
        const float w0 = b2f((u16)((u32)p0.x >> 16));
        const float w1 = b2f((u16)((u32)p0.y >> 16));
        const float w2 = b2f((u16)((u32)p0.z >> 16));
        const float w3 = b2f((u16)((u32)p0.w >> 16));
        aL0 += pkcvt<false>(r0) * w0; aH0 += pkcvt<true>(r0) * w0;
        aL1 += pkcvt<false>(r1) * w1; aH1 += pkcvt<true>(r1) * w1;
        aL2 += pkcvt<false>(r2) * w2; aH2 += pkcvt<true>(r2) * w2;
        aL3 += pkcvt<false>(r3) * w3; aH3 += pkcvt<true>(r3) * w3;
    }
    for (; e < re; ++e) {
        const int pk = bkt[e];
        const u32 r0 = *(const u32*)(B + (size_t)(pk & 0xFFFF) * FD + f);
        const float w0 = b2f((u16)((u32)pk >> 16));
        aL0 += pkcvt<false>(r0) * w0; aH0 += pkcvt<true>(r0) * w0;
    }
    aL0 += pkcvt<false>(us) * di;      // self loop: + di_n*B[n]
    aH0 += pkcvt<true>(us) * di;
    const f32x2 L = (aL0 + aL1) + (aL2 + aL3);
    const f32x2 H = (aH0 + aH1) + (aH2 + aH3);
    float4 r;
    r.x = fmaxf(fmaf(L[0], di, bb.x), 0.f);
    r.y = fmaxf(fmaf(L[1], di, bb.y), 0.f);
    r.z = fmaxf(fmaf(H[0], di, bb.z), 0.f);
    r.w = fmaxf(fmaf(H[1], di, bb.w), 0.f);
    return r;
}

// ======== fused gather(l) + gemm(l+1): 512 threads, 8 waves ========
__global__ __launch_bounds__(512) void k_gg(const int* __restrict__ cnt,
                                            const int* __restrict__ bkt,
                                            const u8* __restrict__ Bin,
                                            const float* __restrict__ bias,
                                            const u16* __restrict__ WTn,
                                            u8* __restrict__ Bout) {
    __shared__ u16 sA[16][FD + 8];   // +16B row pad (R12: conflicts 2.8M->0.4M)
    const int tid = threadIdx.x;
    const int wave = tid >> 6;       // 0..7
    const int lane = tid & 63;
    const int nb = blockIdx.x * 16;  // 3125 blocks exact
    {
        const int half = lane >> 5;
        const int n = nb + wave * 2 + half;
        const int f = (lane & 31) * 4;
        const int cn = cnt[n];
        const int rs = n * CAP;
        const float di = rsqrtf((float)(cn + 1));
        const float4 bb = *(const float4*)(bias + f);
        const float4 r = gather_node<true>(rs, rs + cn, bkt, Bin, di, n, bb, f);
        ushort4 o;
        o.x = f2b(r.x); o.y = f2b(r.y); o.z = f2b(r.z); o.w = f2b(r.w);
        *(ushort4*)&sA[wave * 2 + half][f] = o;
    }
    __syncthreads();
    const int ct = wave;
    const int m = lane & 15;
    const int q = lane >> 4;
    f32x4 acc = (f32x4){0.f, 0.f, 0.f, 0.f};
    const u16* wrow = WTn + (size_t)m * FD + q * 8 + (size_t)ct * 16 * FD;
#pragma unroll
    for (int kb = 0; kb < 4; ++kb) {
        bf16x8 af = *(const bf16x8*)&sA[m][q * 8 + kb * 32];
        bf16x8 bf = *(const bf16x8*)(wrow + kb * 32);
        acc = __builtin_amdgcn_mfma_f32_16x16x32_bf16(af, bf, acc, 0, 0, 0);
    }
#pragma unroll
    for (int r = 0; r < 4; ++r)
        Bout[(size_t)(nb + q * 4 + r) * FD + ct * 16 + m] = f2p(acc[r]);
}

// ======== fused final gather + mean-pool + head (1024 thr, 1 block/graph) ==
__global__ __launch_bounds__(1024) void k_gpool(const int* __restrict__ cnt,
                                                const int* __restrict__ bkt,
                                                const u8* __restrict__ B,
                                                const float* __restrict__ bias,
                                                const int* __restrict__ batch,
                                                const float* __restrict__ lin_w,
                                                const float* __restrict__ lin_b,
                                                float* __restrict__ out) {
    __shared__ float sfeat[32][FD + 4];   // +4 pad: break 4-way bank aliasing
    __shared__ float hm[FD];
    __shared__ int bnd[2];
    __shared__ float part2[2 * NC];
    const int g = blockIdx.x;                          // NG blocks
    const int tid = threadIdx.x;
    const int lane = tid & 63;
    const int slot = (tid >> 6) * 2 + (lane >> 5);     // 0..31
    const int f = (lane & 31) * 4;
    if (tid < 2) {
        const int key = g + tid;
        int lo = 0, hi = NN;
        while (lo < hi) {
            const int mid = (lo + hi) >> 1;
            if (batch[mid] < key) lo = mid + 1; else hi = mid;
        }
        bnd[tid] = lo;
    }
    __syncthreads();
    const int r0 = bnd[0], r1 = bnd[1];
    const float4 bb = *(const float4*)(bias + f);
    float s0 = 0.f, s1 = 0.f, s2 = 0.f, s3 = 0.f;
    for (int r = r0 + slot; r < r1; r += 32) {
        const int cn = cnt[r];
        const int rs = r * CAP;
        const float di = rsqrtf((float)(cn + 1));
        const float4 v = gather_node<false>(rs, rs + cn, bkt, B, di, r, bb, f);
        s0 += v.x; s1 += v.y; s2 += v.z; s3 += v.w;
    }
    sfeat[slot][f] = s0;
    sfeat[slot][f + 1] = s1;
    sfeat[slot][f + 2] = s2;
    sfeat[slot][f + 3] = s3;
    __syncthreads();
    if (tid < 128) {
        float tot = 0.f;
#pragma unroll
        for (int s = 0; s < 32; ++s) tot += sfeat[s][tid];
        const float mean = tot / fmaxf((float)(r1 - r0), 1.0f);
        hm[tid] = mean;
        out[(size_t)g * FD + tid] = mean;
    }
    __syncthreads();
    if (tid < 128) {
        const float hv = hm[tid];
        const int wv = tid >> 6;
#pragma unroll
        for (int c = 0; c < NC; ++c) {
            float p = hv * lin_w[tid * NC + c];
#pragma unroll
            for (int o = 32; o > 0; o >>= 1) p += __shfl_down(p, o, 64);
            if ((tid & 63) == 0) part2[c * 2 + wv] = p;
        }
    }
    __syncthreads();
    if (tid == 0) {
        float lg[NC];
        float m = -1e30f;
#pragma unroll
        for (int c = 0; c < NC; ++c) {
            lg[c] = part2[2 * c] + part2[2 * c + 1] + lin_b[c];
            m = fmaxf(m, lg[c]);
        }
        float s = 0.f;
#pragma unroll
        for (int c = 0; c < NC; ++c) s += expf(lg[c] - m);
        const float lse = m + logf(s);
        float* o = out + (size_t)NG * FD + (size_t)g * NC;
#pragma unroll
        for (int c = 0; c < NC; ++c) o[c] = lg[c] - lse;
    }
}

extern "C" void kernel_launch(void* const* d_in, const int* in_sizes, int n_in,
                              void* d_out, int out_size, void* d_ws, size_t ws_size,
                              hipStream_t stream) {
    const float* x     = (const float*)d_in[0];   // [NN,128] fp32
    const float* W     = (const float*)d_in[1];   // [3,128,128] fp32
    const float* bias  = (const float*)d_in[2];   // [3,128] fp32
    const float* lin_w = (const float*)d_in[3];   // [128,10] fp32
    const float* lin_b = (const float*)d_in[4];   // [10] fp32
    const int*   src   = (const int*)d_in[5];     // edge_index[0], int32
    const int*   dst   = src + NE;                // edge_index[1]
    const int*   batch = (const int*)d_in[6];     // [NN] int32

    // workspace layout (~26 MB), all chunks 16B-aligned
    u8*    B0     = (u8*)d_ws;                        // NN*FD fp8 (unscaled)
    u8*    B1     = B0 + (size_t)NN * FD;             // NN*FD fp8 (unscaled)
    u16*   WT     = (u16*)(B1 + (size_t)NN * FD);     // NL*FD*FD bf16 (transposed; l=0 slot unused)
    int*   bkt    = (int*)(WT + (size_t)NL * FD * FD); // NN*CAP bucket CSR (packed id|w)
    int*   cnt    = bkt + (size_t)NN * CAP;           // NN
    float* out    = (float*)d_out;                    // hG [NG*FD] ++ logsm [NG*NC]

    // --- fused front-end: XCD-binned scatter + gemm0 + WT cvt, ONE kernel ---
    (void)hipMemsetAsync(cnt, 0, NN * sizeof(int), stream);
    k_front<<<FRONT_B, 256, 0, stream>>>(src, dst, cnt, bkt, W, WT, x, B0);
    // --- pack dinv[src] (bf16) into bucket entries' high 16 bits ---
    k_patch<<<PATCH_B, 256, 0, stream>>>(cnt, bkt);

    // --- layers: fused gather+gemm x2; fused gather+pool+head ---
    k_gg<<<NN / 16, 512, 0, stream>>>(cnt, bkt, B0, bias,
                                      WT + (size_t)1 * FD * FD, B1);
    k_gg<<<NN / 16, 512, 0, stream>>>(cnt, bkt, B1, bias + FD,
                                      WT + (size_t)2 * FD * FD, B0);
    k_gpool<<<NG, 1024, 0, stream>>>(cnt, bkt, B0, bias + 2 * FD,
                                     batch, lin_w, lin_b, out);
}

// Round 6
// 213.268 us; speedup vs baseline: 1.0724x; 1.0724x over previous
//
#include <hip/hip_runtime.h>
#include <hip/hip_bf16.h>
#include <hip/hip_fp8.h>

// Problem constants (fixed by the reference setup)
#define NN 50000     // nodes
#define NE 800000    // edges
#define FD 128       // feature dim (D_FEAT == DIM_H)
#define NG 512       // graphs
#define NC 10        // classes
#define NL 3         // layers
#define CAP 64       // bucket capacity (deg ~ Poisson(16); max over 50K ~ 33)
#define GEMM_B 782   // ceil(3125/4): 4 waves/block, 16 rows/wave
#define COMP_B 910   // GEMM_B + CVT blocks (128)
#define NBIN 196     // ceil(NN/256); bin = dst >> 8 (256 nodes/bin)
#define BCAP 4800    // per-bin edge capacity: Poisson(4096) + 11 sigma
#define CHUNK 4096   // edges per partition block
#define NCHUNK 196   // ceil(NE/CHUNK)
#define PART_B (NCHUNK + COMP_B)
#define PATCH_B 12500 // NN*CAP/256

typedef unsigned short u16;
typedef unsigned char u8;
typedef unsigned int u32;
typedef short bf16x8 __attribute__((ext_vector_type(8)));
typedef float f32x4 __attribute__((ext_vector_type(4)));
typedef float f32x2 __attribute__((ext_vector_type(2)));

__device__ __forceinline__ float b2f(u16 v) {
    union { u32 u; float f; } c; c.u = ((u32)v) << 16; return c.f;
}
__device__ __forceinline__ u16 f2b(float f) {
    __hip_bfloat16 h = __float2bfloat16(f);   // RTNE
    return *(u16*)&h;
}
// OCP e4m3 (gfx950 HW cvt). B rows stored fp8 UNSCALED; the edge weight
// dinv[src] is PACKED (bf16) into the high 16 bits of each bucket entry by
// k_patch, so gathers pay ZERO extra loads for normalization.
__device__ __forceinline__ float p2f(u8 b) {
    __hip_fp8_e4m3 h; h.__x = b; return (float)h;
}
__device__ __forceinline__ u8 f2p(float f) {
    __hip_fp8_e4m3 h(f); return h.__x;
}

// HW packed fp8->f32 (2 lanes/instr). Word-select must be a template const
// (instruction immediate — R3 compile fail).
#if defined(__has_builtin)
#if __has_builtin(__builtin_amdgcn_cvt_pk_f32_fp8)
#define HAVE_PKCVT 1
#endif
#endif
template<bool HI>
__device__ __forceinline__ f32x2 pkcvt(u32 u) {
#ifdef HAVE_PKCVT
    return __builtin_amdgcn_cvt_pk_f32_fp8((int)u, HI);
#else
    f32x2 r;
    r[0] = p2f((u8)(HI ? (u >> 16) : u));
    r[1] = p2f((u8)(HI ? (u >> 24) : (u >> 8)));
    return r;
#endif
}

// ======== pass 1: LDS radix partition of edges by dst-bin + GEMM0/CVT ======
// R0-R5 lesson: every scatter variant (800K global atomics + 800K dependent
// scattered stores = 1.6M random line-ops) lands at 51-58us ~= 29 line-ops/ns
// regardless of bytes — the wall is scattered-op COUNT. This partition does
// the binning with LDS atomics and emits edges as ~21-edge contiguous runs:
// ~40K global atomics + ~80K segment stores = 8% of the old op count.
// Edge packed as (d<<16)|s (both < 65536). GEMM/CVT blocks ride along and
// hide under the partition as before.
__global__ __launch_bounds__(256) void k_part(const int* __restrict__ src,
                                              const int* __restrict__ dst,
                                              int* __restrict__ gcnt,
                                              int* __restrict__ ebuf,
                                              const float* __restrict__ W,
                                              u16* __restrict__ wt,
                                              const float* __restrict__ x,
                                              u8* __restrict__ Bout) {
    __shared__ int stage[CHUNK];    // 16KB bin-ordered edge staging
    __shared__ int hist[NBIN];
    __shared__ int lbase[NBIN];
    __shared__ int gbase[NBIN];
    __shared__ int scan[256];
    const int bid = blockIdx.x;
    const int tid = threadIdx.x;
    if (bid >= NCHUNK) {
        const int q = bid - NCHUNK;
        if (q < GEMM_B) {
            // ---- gemm0: x(fp32) @ W0 -> B0 (fp8, UNSCALED) ----
            // a_frag: A[m=lane&15][k=q*8+j]; b_frag: W[k][n=ct*16+m];
            // C/D: col=lane&15, row=q*4+reg   [verified m89/m91]
            const int wid = q * 4 + (tid >> 6);
            if (wid >= 3125) return;
            const int row0 = wid * 16;
            const int lane = tid & 63;
            const int m = lane & 15;
            const int qq = lane >> 4;
            f32x4 acc[8];
#pragma unroll
            for (int ct = 0; ct < 8; ++ct) acc[ct] = (f32x4){0.f, 0.f, 0.f, 0.f};
            const float* arow = x + (size_t)(row0 + m) * FD + qq * 8;
            const float* wbase = W + (size_t)qq * 8 * FD + m;
#pragma unroll
            for (int kb = 0; kb < 4; ++kb) {
                const float4 p0 = *(const float4*)(arow + kb * 32);
                const float4 p1 = *(const float4*)(arow + kb * 32 + 4);
                bf16x8 af;
                af[0] = (short)f2b(p0.x); af[1] = (short)f2b(p0.y);
                af[2] = (short)f2b(p0.z); af[3] = (short)f2b(p0.w);
                af[4] = (short)f2b(p1.x); af[5] = (short)f2b(p1.y);
                af[6] = (short)f2b(p1.z); af[7] = (short)f2b(p1.w);
#pragma unroll
                for (int ct = 0; ct < 8; ++ct) {
                    const float* wp = wbase + (size_t)kb * 32 * FD + ct * 16;
                    bf16x8 bf;
#pragma unroll
                    for (int j = 0; j < 8; ++j)
                        bf[j] = (short)f2b(wp[(size_t)j * FD]);
                    acc[ct] = __builtin_amdgcn_mfma_f32_16x16x32_bf16(af, bf,
                                                                      acc[ct], 0, 0, 0);
                }
            }
#pragma unroll
            for (int ct = 0; ct < 8; ++ct)
#pragma unroll
                for (int r = 0; r < 4; ++r)
                    Bout[(size_t)(row0 + qq * 4 + r) * FD + ct * 16 + m] =
                        f2p(acc[ct][r]);
        } else {
            // ---- WT convert, layers 1..2 only (layer 0 read raw above) ----
            const int c = (q - GEMM_B) * 256 + tid + FD * FD;
            const int l = c >> 14, rr = c & 16383, k = rr >> 7, n = rr & 127;
            wt[(l << 14) + n * FD + k] = f2b(W[c]);
        }
        return;
    }
    // ---- partition branch: 4096 edges, 16/thread ----
    if (tid < NBIN) hist[tid] = 0;
    __syncthreads();
    const int e00 = bid * CHUNK;
    int dv[16], sv[16], pp[16];
#pragma unroll
    for (int k = 0; k < 4; ++k) {
        const int e = e00 + k * 1024 + tid * 4;
        if (e < NE) {                       // NE%4==0 -> whole int4 in-bounds
            const int4 d4 = *(const int4*)(dst + e);
            const int4 s4 = *(const int4*)(src + e);
            dv[k*4+0] = d4.x; dv[k*4+1] = d4.y; dv[k*4+2] = d4.z; dv[k*4+3] = d4.w;
            sv[k*4+0] = s4.x; sv[k*4+1] = s4.y; sv[k*4+2] = s4.z; sv[k*4+3] = s4.w;
        } else {
            dv[k*4+0] = dv[k*4+1] = dv[k*4+2] = dv[k*4+3] = -1;
        }
    }
#pragma unroll
    for (int k = 0; k < 16; ++k)
        if (dv[k] >= 0) pp[k] = atomicAdd(&hist[((u32)dv[k]) >> 8], 1);
    __syncthreads();
    // block-wide inclusive scan of hist (Hillis-Steele over 256 threads)
    const int hv = (tid < NBIN) ? hist[tid] : 0;
    scan[tid] = hv;
    __syncthreads();
    for (int o = 1; o < 256; o <<= 1) {
        const int t = (tid >= o) ? scan[tid - o] : 0;
        __syncthreads();
        scan[tid] += t;
        __syncthreads();
    }
    if (tid < NBIN) {
        lbase[tid] = scan[tid] - hv;                     // exclusive prefix
        gbase[tid] = atomicAdd(&gcnt[tid], hv);          // reserve bin space
    }
    const int total = scan[255];
    __syncthreads();
#pragma unroll
    for (int k = 0; k < 16; ++k)
        if (dv[k] >= 0)
            stage[lbase[((u32)dv[k]) >> 8] + pp[k]] = (dv[k] << 16) | sv[k];
    __syncthreads();
    // write out: consecutive i = same-bin runs (avg ~21 edges = 84B segments)
    for (int i = tid; i < total; i += 256) {
        const int pv = stage[i];
        const int b = ((u32)pv) >> 24;                   // (d>>16)>>8
        const int idx = gbase[b] + (i - lbase[b]);
        if (idx < BCAP) ebuf[(size_t)b * BCAP + idx] = pv;   // OOB-safe
    }
}

// ======== pass 2: per-bin bucket build in LDS, coalesced write-out ========
// One block per bin (256 nodes). LDS atomics for cnt/slots (no global
// scatter); 64KB bucket region + cnt written fully coalesced. Garbage in
// invalid slots is never read (cnt-guarded everywhere).
__global__ __launch_bounds__(256) void k_build(const int* __restrict__ gcnt,
                                               const int* __restrict__ ebuf,
                                               int* __restrict__ cnt,
                                               int* __restrict__ bkt) {
    __shared__ int cl[256];
    __shared__ int bl[256 * CAP];    // 64KB
    const int b = blockIdx.x;
    const int tid = threadIdx.x;
    cl[tid] = 0;
    __syncthreads();
    const int m = min(gcnt[b], BCAP);
    const int* eb = ebuf + (size_t)b * BCAP;
    for (int i = tid; i < m; i += 256) {
        const int pv = eb[i];
        const int ld = (((u32)pv) >> 16) & 255;
        const int slot = atomicAdd(&cl[ld], 1);
        if (slot < CAP) bl[ld * CAP + slot] = pv & 0xFFFF;
    }
    __syncthreads();
    const int n0 = b * 256;
    const int nh = min(256, NN - n0);         // nodes in this bin
    if (tid < nh) cnt[n0 + tid] = cl[tid];
    int4* dstp = (int4*)(bkt + (size_t)n0 * CAP);
    const int4* srcp = (const int4*)bl;
    const int ti = nh * (CAP / 4);
    for (int i = tid; i < ti; i += 256) dstp[i] = srcp[i];
}

// ======== bucket weight patch: entry := src | bf16(dinv[src]) << 16 ========
__global__ __launch_bounds__(256) void k_patch(const int* __restrict__ cnt,
                                               int* __restrict__ bkt) {
    const int i = blockIdx.x * 256 + threadIdx.x;   // NN*CAP exact
    const int d = i >> 6;
    const int s = i & 63;
    if (s < cnt[d]) {
        const int v = bkt[i];                       // raw src id (<50000, 16b)
        const u32 w = (u32)f2b(rsqrtf((float)(cnt[v] + 1)));
        bkt[i] = (int)(((u32)v & 0xFFFFu) | (w << 16));
    }
}

// ======== half-wave gather on UNSCALED fp8 rows (packed bucket CSR) ========
// h[n] = relu(di_n * (sum_in w_s*B[s] + di_n*B[n]) + bias); rows 128 B fp8.
// W8: 8 rows in flight (k_gg). k_gpool stays 4-wide: its 1024-thr blocks sit
// at the 2-blocks/CU VGPR cliff; 8-wide would halve gpool occupancy.
template<bool W8>
__device__ __forceinline__ float4 gather_node(const int rs, const int re,
                                              const int* __restrict__ bkt,
                                              const u8* __restrict__ B,
                                              const float di, const int n,
                                              const float4 bb, const int f) {
    const u32 us = *(const u32*)(B + (size_t)n * FD + f);   // self row (early)
    f32x2 aL0 = {0.f, 0.f}, aL1 = {0.f, 0.f}, aL2 = {0.f, 0.f}, aL3 = {0.f, 0.f};
    f32x2 aH0 = {0.f, 0.f}, aH1 = {0.f, 0.f}, aH2 = {0.f, 0.f}, aH3 = {0.f, 0.f};
    int e = rs;
    if (W8) {
        for (; e + 8 <= re; e += 8) {
            const int4 p0 = *(const int4*)(bkt + e);     // rs 16B-aligned
            const int4 p1 = *(const int4*)(bkt + e + 4);
            const u32 r0 = *(const u32*)(B + (size_t)(p0.x & 0xFFFF) * FD + f);
            const u32 r1 = *(const u32*)(B + (size_t)(p0.y & 0xFFFF) * FD + f);
            const u32 r2 = *(const u32*)(B + (size_t)(p0.z & 0xFFFF) * FD + f);
            const u32 r3 = *(const u32*)(B + (size_t)(p0.w & 0xFFFF) * FD + f);
            const u32 r4 = *(const u32*)(B + (size_t)(p1.x & 0xFFFF) * FD + f);
            const u32 r5 = *(const u32*)(B + (size_t)(p1.y & 0xFFFF) * FD + f);
            const u32 r6 = *(const u32*)(B + (size_t)(p1.z & 0xFFFF) * FD + f);
            const u32 r7 = *(const u32*)(B + (size_t)(p1.w & 0xFFFF) * FD + f);
            const float w0 = b2f((u16)((u32)p0.x >> 16));
            const float w1 = b2f((u16)((u32)p0.y >> 16));
            const float w2 = b2f((u16)((u32)p0.z >> 16));
            const float w3 = b2f((u16)((u32)p0.w >> 16));
            const float w4 = b2f((u16)((u32)p1.x >> 16));
            const float w5 = b2f((u16)((u32)p1.y >> 16));
            const float w6 = b2f((u16)((u32)p1.z >> 16));
            const float w7 = b2f((u16)((u32)p1.w >> 16));
            aL0 += pkcvt<false>(r0) * w0; aH0 += pkcvt<true>(r0) * w0;
            aL1 += pkcvt<false>(r1) * w1; aH1 += pkcvt<true>(r1) * w1;
            aL2 += pkcvt<false>(r2) * w2; aH2 += pkcvt<true>(r2) * w2;
            aL3 += pkcvt<false>(r3) * w3; aH3 += pkcvt<true>(r3) * w3;
            aL0 += pkcvt<false>(r4) * w4; aH0 += pkcvt<true>(r4) * w4;
            aL1 += pkcvt<false>(r5) * w5; aH1 += pkcvt<true>(r5) * w5;
            aL2 += pkcvt<false>(r6) * w6; aH2 += pkcvt<true>(r6) * w6;
            aL3 += pkcvt<false>(r7) * w7; aH3 += pkcvt<true>(r7) * w7;
        }
    }
    for (; e + 4 <= re; e += 4) {
        const int4 p0 = *(const int4*)(bkt + e);
        const u32 r0 = *(const u32*)(B + (size_t)(p0.x & 0xFFFF) * FD + f);
        const u32 r1 = *(const u32*)(B + (size_t)(p0.y & 0xFFFF) * FD + f);
        const u32 r2 = *(const u32*)(B + (size_t)(p0.z & 0xFFFF) * FD + f);
        const u32 r3 = *(const u32*)(B + (size_t)(p0.w & 0xFFFF) * FD + f);
        const float w0 = b2f((u16)((u32)p0.x >> 16));
        const float w1 = b2f((u16)((u32)p0.y >> 16));
        const float w2 = b2f((u16)((u32)p0.z >> 16));
        const float w3 = b2f((u16)((u32)p0.w >> 16));
        aL0 += pkcvt<false>(r0) * w0; aH0 += pkcvt<true>(r0) * w0;
        aL1 += pkcvt<false>(r1) * w1; aH1 += pkcvt<true>(r1) * w1;
        aL2 += pkcvt<false>(r2) * w2; aH2 += pkcvt<true>(r2) * w2;
        aL3 += pkcvt<false>(r3) * w3; aH3 += pkcvt<true>(r3) * w3;
    }
    for (; e < re; ++e) {
        const int pk = bkt[e];
        const u32 r0 = *(const u32*)(B + (size_t)(pk & 0xFFFF) * FD + f);
        const float w0 = b2f((u16)((u32)pk >> 16));
        aL0 += pkcvt<false>(r0) * w0; aH0 += pkcvt<true>(r0) * w0;
    }
    aL0 += pkcvt<false>(us) * di;      // self loop: + di_n*B[n]
    aH0 += pkcvt<true>(us) * di;
    const f32x2 L = (aL0 + aL1) + (aL2 + aL3);
    const f32x2 H = (aH0 + aH1) + (aH2 + aH3);
    float4 r;
    r.x = fmaxf(fmaf(L[0], di, bb.x), 0.f);
    r.y = fmaxf(fmaf(L[1], di, bb.y), 0.f);
    r.z = fmaxf(fmaf(H[0], di, bb.z), 0.f);
    r.w = fmaxf(fmaf(H[1], di, bb.w), 0.f);
    return r;
}

// ======== fused gather(l) + gemm(l+1): 512 threads, 8 waves ========
__global__ __launch_bounds__(512) void k_gg(const int* __restrict__ cnt,
                                            const int* __restrict__ bkt,
                                            const u8* __restrict__ Bin,
                                            const float* __restrict__ bias,
                                            const u16* __restrict__ WTn,
                                            u8* __restrict__ Bout) {
    __shared__ u16 sA[16][FD + 8];   // +16B row pad (R12: conflicts 2.8M->0.4M)
    const int tid = threadIdx.x;
    const int wave = tid >> 6;       // 0..7
    const int lane = tid & 63;
    const int nb = blockIdx.x * 16;  // 3125 blocks exact
    {
        const int half = lane >> 5;
        const int n = nb + wave * 2 + half;
        const int f = (lane & 31) * 4;
        const int cn = cnt[n];
        const int rs = n * CAP;
        const float di = rsqrtf((float)(cn + 1));
        const float4 bb = *(const float4*)(bias + f);
        const float4 r = gather_node<true>(rs, rs + cn, bkt, Bin, di, n, bb, f);
        ushort4 o;
        o.x = f2b(r.x); o.y = f2b(r.y); o.z = f2b(r.z); o.w = f2b(r.w);
        *(ushort4*)&sA[wave * 2 + half][f] = o;
    }
    __syncthreads();
    const int ct = wave;
    const int m = lane & 15;
    const int q = lane >> 4;
    f32x4 acc = (f32x4){0.f, 0.f, 0.f, 0.f};
    const u16* wrow = WTn + (size_t)m * FD + q * 8 + (size_t)ct * 16 * FD;
#pragma unroll
    for (int kb = 0; kb < 4; ++kb) {
        bf16x8 af = *(const bf16x8*)&sA[m][q * 8 + kb * 32];
        bf16x8 bf = *(const bf16x8*)(wrow + kb * 32);
        acc = __builtin_amdgcn_mfma_f32_16x16x32_bf16(af, bf, acc, 0, 0, 0);
    }
#pragma unroll
    for (int r = 0; r < 4; ++r)
        Bout[(size_t)(nb + q * 4 + r) * FD + ct * 16 + m] = f2p(acc[r]);
}

// ======== fused final gather + mean-pool + head (1024 thr, 1 block/graph) ==
__global__ __launch_bounds__(1024) void k_gpool(const int* __restrict__ cnt,
                                                const int* __restrict__ bkt,
                                                const u8* __restrict__ B,
                                                const float* __restrict__ bias,
                                                const int* __restrict__ batch,
                                                const float* __restrict__ lin_w,
                                                const float* __restrict__ lin_b,
                                                float* __restrict__ out) {
    __shared__ float sfeat[32][FD + 4];   // +4 pad: break 4-way bank aliasing
    __shared__ float hm[FD];
    __shared__ int bnd[2];
    __shared__ float part2[2 * NC];
    const int g = blockIdx.x;                          // NG blocks
    const int tid = threadIdx.x;
    const int lane = tid & 63;
    const int slot = (tid >> 6) * 2 + (lane >> 5);     // 0..31
    const int f = (lane & 31) * 4;
    if (tid < 2) {
        const int key = g + tid;
        int lo = 0, hi = NN;
        while (lo < hi) {
            const int mid = (lo + hi) >> 1;
            if (batch[mid] < key) lo = mid + 1; else hi = mid;
        }
        bnd[tid] = lo;
    }
    __syncthreads();
    const int r0 = bnd[0], r1 = bnd[1];
    const float4 bb = *(const float4*)(bias + f);
    float s0 = 0.f, s1 = 0.f, s2 = 0.f, s3 = 0.f;
    for (int r = r0 + slot; r < r1; r += 32) {
        const int cn = cnt[r];
        const int rs = r * CAP;
        const float di = rsqrtf((float)(cn + 1));
        const float4 v = gather_node<false>(rs, rs + cn, bkt, B, di, r, bb, f);
        s0 += v.x; s1 += v.y; s2 += v.z; s3 += v.w;
    }
    sfeat[slot][f] = s0;
    sfeat[slot][f + 1] = s1;
    sfeat[slot][f + 2] = s2;
    sfeat[slot][f + 3] = s3;
    __syncthreads();
    if (tid < 128) {
        float tot = 0.f;
#pragma unroll
        for (int s = 0; s < 32; ++s) tot += sfeat[s][tid];
        const float mean = tot / fmaxf((float)(r1 - r0), 1.0f);
        hm[tid] = mean;
        out[(size_t)g * FD + tid] = mean;
    }
    __syncthreads();
    if (tid < 128) {
        const float hv = hm[tid];
        const int wv = tid >> 6;
#pragma unroll
        for (int c = 0; c < NC; ++c) {
            float p = hv * lin_w[tid * NC + c];
#pragma unroll
            for (int o = 32; o > 0; o >>= 1) p += __shfl_down(p, o, 64);
            if ((tid & 63) == 0) part2[c * 2 + wv] = p;
        }
    }
    __syncthreads();
    if (tid == 0) {
        float lg[NC];
        float m = -1e30f;
#pragma unroll
        for (int c = 0; c < NC; ++c) {
            lg[c] = part2[2 * c] + part2[2 * c + 1] + lin_b[c];
            m = fmaxf(m, lg[c]);
        }
        float s = 0.f;
#pragma unroll
        for (int c = 0; c < NC; ++c) s += expf(lg[c] - m);
        const float lse = m + logf(s);
        float* o = out + (size_t)NG * FD + (size_t)g * NC;
#pragma unroll
        for (int c = 0; c < NC; ++c) o[c] = lg[c] - lse;
    }
}

extern "C" void kernel_launch(void* const* d_in, const int* in_sizes, int n_in,
                              void* d_out, int out_size, void* d_ws, size_t ws_size,
                              hipStream_t stream) {
    const float* x     = (const float*)d_in[0];   // [NN,128] fp32
    const float* W     = (const float*)d_in[1];   // [3,128,128] fp32
    const float* bias  = (const float*)d_in[2];   // [3,128] fp32
    const float* lin_w = (const float*)d_in[3];   // [128,10] fp32
    const float* lin_b = (const float*)d_in[4];   // [10] fp32
    const int*   src   = (const int*)d_in[5];     // edge_index[0], int32
    const int*   dst   = src + NE;                // edge_index[1]
    const int*   batch = (const int*)d_in[6];     // [NN] int32

    // workspace layout (~26 MB), all chunks 16B-aligned
    u8*    B0     = (u8*)d_ws;                        // NN*FD fp8 (unscaled)
    u8*    B1     = B0 + (size_t)NN * FD;             // NN*FD fp8 (unscaled)
    u16*   WT     = (u16*)(B1 + (size_t)NN * FD);     // NL*FD*FD bf16 (transposed; l=0 slot unused)
    int*   bkt    = (int*)(WT + (size_t)NL * FD * FD); // NN*CAP bucket CSR (packed id|w)
    int*   cnt    = bkt + (size_t)NN * CAP;           // NN
    int*   gcnt   = cnt + NN;                         // NBIN bin cursors
    // ebuf (NBIN*BCAP ints = 3.76MB) aliases B1: B1 is dead until k_gg L1,
    // and k_build (the last ebuf reader) completes before that launch.
    int*   ebuf   = (int*)B1;
    float* out    = (float*)d_out;                    // hG [NG*FD] ++ logsm [NG*NC]

    // --- front-end: partition(+gemm0+cvt) -> bucket build -> weight patch ---
    (void)hipMemsetAsync(gcnt, 0, NBIN * sizeof(int), stream);
    k_part<<<PART_B, 256, 0, stream>>>(src, dst, gcnt, ebuf, W, WT, x, B0);
    k_build<<<NBIN, 256, 0, stream>>>(gcnt, ebuf, cnt, bkt);
    k_patch<<<PATCH_B, 256, 0, stream>>>(cnt, bkt);

    // --- layers: fused gather+gemm x2; fused gather+pool+head ---
    k_gg<<<NN / 16, 512, 0, stream>>>(cnt, bkt, B0, bias,
                                      WT + (size_t)1 * FD * FD, B1);
    k_gg<<<NN / 16, 512, 0, stream>>>(cnt, bkt, B1, bias + FD,
                                      WT + (size_t)2 * FD * FD, B0);
    k_gpool<<<NG, 1024, 0, stream>>>(cnt, bkt, B0, bias + 2 * FD,
                                     batch, lin_w, lin_b, out);
}